// Round 4
// baseline (1056.983 us; speedup 1.0000x reference)
//
#include <hip/hip_runtime.h>

#define BATCH 4096
#define SEQ   2048
#define EMB   10
#define HID   50
#define VOCAB 14
#define NTILE 13       // 13 M-tiles of 16 cover 200 gate rows (+8 pad)
#define TROW  2052     // token row stride bytes (u8): /4=513 ≡ 1 mod 32 -> conflict-free

using bf16x8 = __attribute__((ext_vector_type(8))) short;
using f32x4  = __attribute__((ext_vector_type(4))) float;

__device__ __forceinline__ short f2bf(float f) {
  unsigned u = __builtin_bit_cast(unsigned, f);
  u = (u + 0x7FFFu + ((u >> 16) & 1u)) >> 16;   // round-to-nearest-even
  return (short)u;
}
__device__ __forceinline__ float fsigm(float x) {
  return __builtin_amdgcn_rcpf(1.0f + __builtin_amdgcn_exp2f(x * -1.44269504f));
}

// ---------------------------------------------------------------------------
// Pack A fragments (bf16, pre-scaled) for mfma_f32_16x16x32_bf16.
// Tile t row m (0..15): q=m>>2, g=m&3 -> hidden jh = 13*q + t, gate g.
//   (C-layout row = quad*4 + reg  =>  lane quad jj owns jh = 13*jj + t, and
//    its 4 acc regs are gates i,f,g,o of that jh. The 13*jj+t map puts the 4
//    h-writing lanes of a wave in 4 different LDS words.)
// Original gate row R = g*50 + jh. Rows scaled by -log2e (i,f,o) / -2log2e (g)
// so the epilogue is rcp(1+exp2(acc)) directly.
//   k < 50 : W_hh[R][k]*scale ; k >= 50 : gxi[v=k-50][R]*scale (emb/W_ih/biases)
// ---------------------------------------------------------------------------
__global__ void prep_kernel(const float* __restrict__ emb,  const float* __restrict__ W_ih,
                            const float* __restrict__ W_hh, const float* __restrict__ b_ih,
                            const float* __restrict__ b_hh, short* __restrict__ Apack) {
  int idx = blockIdx.x * 256 + threadIdx.x;       // total NTILE*2*64*8 = 13312
  if (idx >= NTILE * 2 * 64 * 8) return;
  int j    = idx & 7;
  int lane = (idx >> 3) & 63;
  int kf   = (idx >> 9) & 1;
  int t    = idx >> 10;
  int m    = lane & 15;
  int q    = m >> 2, g = m & 3;
  int jh   = 13 * q + t;
  int k    = kf * 32 + (lane >> 4) * 8 + j;
  float v = 0.0f;
  if (jh < HID) {
    int R = g * HID + jh;
    float scale = (g == 2) ? -2.885390082f : -1.442695041f;
    if (k < HID) {
      v = W_hh[R * HID + k] * scale;
    } else {
      int vo = k - HID;                            // vocab id 0..13
      float s = b_ih[R] + b_hh[R];
      for (int e = 0; e < EMB; ++e) s += emb[vo * EMB + e] * W_ih[R * EMB + e];
      v = s * scale;
    }
  }
  Apack[idx] = f2bf(v);
}

// ---------------------------------------------------------------------------
// Main: 256 wgs x 1024 threads (16 waves), one wg owns 16 batch rows.
// h-buffer rows are 128 B with XOR-swizzled octets: k-octet o of batch row b
// sits at byte 128*b + 16*((o+b)&7). All LDS addresses are loop-invariant.
// Tokens live in LDS as u8 for the whole sequence -> no vmem in the loop,
// barriers drain lgkmcnt only. Waves 0..12 compute one tile; all 16 waves
// write the one-hot row (k=50..63) of batch row wv for step T+1.
// ---------------------------------------------------------------------------
__global__ __launch_bounds__(1024, 1) void lstm_kernel(
    const int* __restrict__ tokens, const short* __restrict__ Apack,
    const float* __restrict__ W1, const float* __restrict__ b1,
    const float* __restrict__ W2, const float* __restrict__ b2,
    float* __restrict__ out) {
  __shared__ __align__(16) unsigned char toku8[16 * TROW];   // 32832 B
  __shared__ __align__(16) short hbuf[2][16 * 64];           // 4096 B, swizzled
  __shared__ float hfin[16 * 52];
  __shared__ float mlp_hid[16 * 52];

  const int tid  = threadIdx.x;
  const int lane = tid & 63;
  const int wv   = tid >> 6;
  const int b0   = blockIdx.x * 16;
  const int bB   = lane & 15;          // batch col (B-frag & C col)
  const int jj   = lane >> 4;          // quad
  const bool compute = (wv < NTILE);
  const int jhw  = 13 * jj + wv;       // hidden unit this lane produces
  const bool hval = compute && (jhw < HID);   // excludes jh=50,51 pads

  // persistent A fragments
  bf16x8 Af0 = {}, Af1 = {};
  if (compute) {
    Af0 = *(const bf16x8*)(Apack + ((wv * 2 + 0) * 64 + lane) * 8);
    Af1 = *(const bf16x8*)(Apack + ((wv * 2 + 1) * 64 + lane) * 8);
  }

  // ---- stage tokens (int32 -> u8) and zero hbuf[0]
  for (int i = tid; i < 16 * 512; i += 1024) {        // 8192 int4-groups
    int row = i >> 9, c4 = i & 511;
    int4 tv = *(const int4*)&tokens[(b0 + row) * SEQ + 4 * c4];
    unsigned pk = (tv.x & 0xFF) | ((tv.y & 0xFF) << 8) |
                  ((tv.z & 0xFF) << 16) | ((tv.w & 0xFF) << 24);
    *(unsigned*)&toku8[row * TROW + 4 * c4] = pk;
  }
  if (tid < 1024) hbuf[0][tid] = 0;
  __syncthreads();

  // loop-invariant LDS byte offsets (into hbuf[p], p selected by +2048)
  char* hb = (char*)hbuf;
  const int rb0 = bB * 128 + 16 * ((jj + bB) & 7);          // B-frag octet jj
  const int rb1 = bB * 128 + 16 * (((jj + 4) + bB) & 7);    // octet jj+4
  const int hwb = bB * 128 + 16 * (((jhw >> 3) + bB) & 7) + 2 * (jhw & 7);
  const int ohoct = (lane < 3) ? 6 : 7;                      // one-hot words
  const int ohwd  = (lane < 3) ? (1 + lane) : (lane - 3);
  const int ohb   = wv * 128 + 16 * ((ohoct + wv) & 7) + 4 * ohwd;
  const unsigned char* myrow = &toku8[bB * TROW];   // keep-mask tokens
  const unsigned char* ohrow = &toku8[wv * TROW];   // one-hot tokens

  // one-hot for t=0
  {
    int tk = ohrow[0];
    if (lane < 7) {
      unsigned wb = ((tk == 2 * lane) ? 0x3F80u : 0u) |
                    ((tk == 2 * lane + 1) ? 0x3F800000u : 0u);
      *(unsigned*)(hb + ohb) = wb;
    }
  }

  float c0 = 0.f, h0 = 0.f;
  unsigned mp = 0, ohp = 0;

  for (int t = 0; t < SEQ; t += 16) {
#pragma unroll
    for (int u = 0; u < 16; ++u) {
      const int T  = t + u;
      const int PB = (u & 1) * 2048, PN = PB ^ 2048;
      __syncthreads();   // hbuf[PB] ready; all LDS-only -> lgkmcnt drain

      bf16x8 Bf0, Bf1;
      f32x4 aA = {0.f, 0.f, 0.f, 0.f}, aB = {0.f, 0.f, 0.f, 0.f};
      if (compute) {
        Bf0 = *(const bf16x8*)(hb + PB + rb0);
        Bf1 = *(const bf16x8*)(hb + PB + rb1);
        if ((u & 3) == 0) mp = *(const unsigned*)(myrow + T);   // tokens T..T+3
        aA = __builtin_amdgcn_mfma_f32_16x16x32_bf16(Af0, Bf0, aA, 0, 0, 0);
        aB = __builtin_amdgcn_mfma_f32_16x16x32_bf16(Af1, Bf1, aB, 0, 0, 0);
      }

      // one-hot for step T+1 into hbuf[PN] (tokens only -> off critical path)
      if (u == 0)       ohp = *(const unsigned*)(ohrow + T);      // T..T+3
      if ((u & 3) == 3 && T + 1 < SEQ)
                        ohp = *(const unsigned*)(ohrow + T + 1);  // T+1..T+4
      if (T + 1 < SEQ) {
        int tk = (ohp >> (8 * ((u + 1) & 3))) & 0xFF;
        if (lane < 7) {
          unsigned wb = ((tk == 2 * lane) ? 0x3F80u : 0u) |
                        ((tk == 2 * lane + 1) ? 0x3F800000u : 0u);
          *(unsigned*)(hb + PN + ohb) = wb;
        }
      }

      if (compute) {
        float x0 = aA[0] + aB[0], x1 = aA[1] + aB[1];
        float x2 = aA[2] + aB[2], x3 = aA[3] + aB[3];
        float gi = __builtin_amdgcn_rcpf(1.0f + __builtin_amdgcn_exp2f(x0));
        float gf = __builtin_amdgcn_rcpf(1.0f + __builtin_amdgcn_exp2f(x1));
        float gg = 2.0f * __builtin_amdgcn_rcpf(1.0f + __builtin_amdgcn_exp2f(x2)) - 1.0f;
        float go = __builtin_amdgcn_rcpf(1.0f + __builtin_amdgcn_exp2f(x3));
        float cn = gf * c0 + gi * gg;
        float th = 2.0f * __builtin_amdgcn_rcpf(1.0f + __builtin_amdgcn_exp2f(cn * -2.88539008f)) - 1.0f;
        float hn = go * th;
        const bool keep = (((mp >> (8 * (u & 3))) & 0xFF) != 0);  // PAD keeps state
        c0 = keep ? cn : c0;
        h0 = keep ? hn : h0;
        if (hval) *(short*)(hb + PN + hwb) = f2bf(h0);
      }
    }
  }

  // ---- final h -> MLP -> sigmoid
  if (hval) hfin[bB * 52 + jhw] = h0;
  __syncthreads();
  for (int idx = tid; idx < 16 * 64; idx += 1024) {
    int b = idx >> 6, m = idx & 63;
    if (m < HID) {
      float s = b1[m];
      for (int j2 = 0; j2 < HID; ++j2) s += hfin[b * 52 + j2] * W1[m * HID + j2];
      mlp_hid[b * 52 + m] = s;
    }
  }
  __syncthreads();
  if (tid < 16) {
    float s = b2[0];
    for (int m2 = 0; m2 < HID; ++m2) s += mlp_hid[tid * 52 + m2] * W2[m2];
    out[b0 + tid] = fsigm(s);
  }
}

extern "C" void kernel_launch(void* const* d_in, const int* in_sizes, int n_in,
                              void* d_out, int out_size, void* d_ws, size_t ws_size,
                              hipStream_t stream) {
  const int*   tokens = (const int*)  d_in[0];
  const float* emb    = (const float*)d_in[1];
  const float* W_ih   = (const float*)d_in[2];
  const float* W_hh   = (const float*)d_in[3];
  const float* b_ih   = (const float*)d_in[4];
  const float* b_hh   = (const float*)d_in[5];
  const float* W1     = (const float*)d_in[6];
  const float* b1     = (const float*)d_in[7];
  const float* W2     = (const float*)d_in[8];
  const float* b2     = (const float*)d_in[9];
  float* outp  = (float*)d_out;
  short* Apack = (short*)d_ws;                 // 13312 bf16 = 26.6 KB

  hipLaunchKernelGGL(prep_kernel, dim3(52), dim3(256), 0, stream,
                     emb, W_ih, W_hh, b_ih, b_hh, Apack);
  hipLaunchKernelGGL(lstm_kernel, dim3(BATCH / 16), dim3(1024), 0, stream,
                     tokens, Apack, W1, b1, W2, b2, outp);
}

// Round 5
// 849.687 us; speedup vs baseline: 1.2440x; 1.2440x over previous
//
#include <hip/hip_runtime.h>

#define BATCH 4096
#define SEQ   2048
#define EMB   10
#define HID   50
#define VOCAB 14
#define NTILE 13       // 13 M-tiles of 16 cover 200 gate rows (+8 pad)
#define TROW  2052     // token row stride bytes (u8): /4=513 ≡ 1 mod 32 -> conflict-free

using bf16x8 = __attribute__((ext_vector_type(8))) short;
using f32x4  = __attribute__((ext_vector_type(4))) float;

__device__ __forceinline__ short f2bf(float f) {
  unsigned u = __builtin_bit_cast(unsigned, f);
  u = (u + 0x7FFFu + ((u >> 16) & 1u)) >> 16;   // round-to-nearest-even
  return (short)u;
}
__device__ __forceinline__ float fsigm(float x) {
  return __builtin_amdgcn_rcpf(1.0f + __builtin_amdgcn_exp2f(x * -1.44269504f));
}

// ---------------------------------------------------------------------------
// Pack A fragments (bf16, pre-scaled) for mfma_f32_16x16x32_bf16.
// Tile t row m: q=m>>2, g=m&3 -> hidden jh = 13*q + t, gate g; R = g*50+jh.
// i/f/o rows scaled by -log2e, g rows by -2log2e, so the epilogue works on
// A=exp2(acc) directly (fused-fraction cell, no per-gate rcp).
//   k < 50 : W_hh[R][k]*scale ; k >= 50 : gxi[v=k-50][R]*scale
// ---------------------------------------------------------------------------
__global__ void prep_kernel(const float* __restrict__ emb,  const float* __restrict__ W_ih,
                            const float* __restrict__ W_hh, const float* __restrict__ b_ih,
                            const float* __restrict__ b_hh, short* __restrict__ Apack) {
  int idx = blockIdx.x * 256 + threadIdx.x;       // total NTILE*2*64*8 = 13312
  if (idx >= NTILE * 2 * 64 * 8) return;
  int j    = idx & 7;
  int lane = (idx >> 3) & 63;
  int kf   = (idx >> 9) & 1;
  int t    = idx >> 10;
  int m    = lane & 15;
  int q    = m >> 2, g = m & 3;
  int jh   = 13 * q + t;
  int k    = kf * 32 + (lane >> 4) * 8 + j;
  float v = 0.0f;
  if (jh < HID) {
    int R = g * HID + jh;
    float scale = (g == 2) ? -2.885390082f : -1.442695041f;
    if (k < HID) {
      v = W_hh[R * HID + k] * scale;
    } else {
      int vo = k - HID;                            // vocab id 0..13
      float s = b_ih[R] + b_hh[R];
      for (int e = 0; e < EMB; ++e) s += emb[vo * EMB + e] * W_ih[R * EMB + e];
      v = s * scale;
    }
  }
  Apack[idx] = f2bf(v);
}

// ---------------------------------------------------------------------------
// Main: 256 wgs x 1024 threads (16 waves), one wg owns 16 batch rows.
// Waves 0..12: one tile each — 2 chained MFMAs + fused-fraction epilogue
//   (5 exp2 + 2 rcp per lane-step), nothing else.
// Waves 13..14: one-hot rows for step T+1 (8 batch rows per wave, 8 lanes
//   per row, 7 active) — entirely off the compute waves.
// Wave 15: barrier-only.
// h rows are 128 B XOR-swizzled; tokens staged once to LDS as u8 (no vmem
// in the loop). All LDS addresses loop-invariant.
// ---------------------------------------------------------------------------
__global__ __launch_bounds__(1024, 1) void lstm_kernel(
    const int* __restrict__ tokens, const short* __restrict__ Apack,
    const float* __restrict__ W1, const float* __restrict__ b1,
    const float* __restrict__ W2, const float* __restrict__ b2,
    float* __restrict__ out) {
  __shared__ __align__(16) unsigned char toku8[16 * TROW];   // 32832 B
  __shared__ __align__(16) short hbuf[2][16 * 64];           // 4096 B, swizzled
  __shared__ float hfin[16 * 52];
  __shared__ float mlp_hid[16 * 52];

  const int tid  = threadIdx.x;
  const int lane = tid & 63;
  const int wv   = tid >> 6;
  const int b0   = blockIdx.x * 16;
  const int bB   = lane & 15;          // batch col (B-frag & C col)
  const int jj   = lane >> 4;          // quad
  const bool compute = (wv < NTILE);
  const int jhw  = 13 * jj + wv;       // hidden unit this lane produces
  const bool hval = compute && (jhw < HID);

  // one-hot duty (waves 13,14): row = 8*(wv-13)+(lane>>3), sub = lane&7
  const bool ohdut = (wv == 13 || wv == 14) && ((lane & 7) < 7);
  const int ohrow_i = (wv - 13) * 8 + (lane >> 3);
  const int ohsub   = lane & 7;

  // persistent A fragments
  bf16x8 Af0 = {}, Af1 = {};
  if (compute) {
    Af0 = *(const bf16x8*)(Apack + ((wv * 2 + 0) * 64 + lane) * 8);
    Af1 = *(const bf16x8*)(Apack + ((wv * 2 + 1) * 64 + lane) * 8);
  }

  // ---- stage tokens (int32 -> u8) and zero hbuf[0]
  for (int i = tid; i < 16 * 512; i += 1024) {        // 8192 int4-groups
    int row = i >> 9, c4 = i & 511;
    int4 tv = *(const int4*)&tokens[(b0 + row) * SEQ + 4 * c4];
    unsigned pk = (tv.x & 0xFF) | ((tv.y & 0xFF) << 8) |
                  ((tv.z & 0xFF) << 16) | ((tv.w & 0xFF) << 24);
    *(unsigned*)&toku8[row * TROW + 4 * c4] = pk;
  }
  if (tid < 1024) hbuf[0][tid] = 0;
  __syncthreads();

  // loop-invariant LDS byte offsets
  char* hb = (char*)hbuf;
  const int rb0 = bB * 128 + 16 * ((jj + bB) & 7);          // B-frag octet jj
  const int rb1 = bB * 128 + 16 * (((jj + 4) + bB) & 7);    // octet jj+4
  const int hwb = bB * 128 + 16 * (((jhw >> 3) + bB) & 7) + 2 * (jhw & 7);
  const int ohoct = (ohsub < 3) ? 6 : 7;                    // k-bytes 100+4*sub
  const int ohwd  = (ohsub < 3) ? (1 + ohsub) : (ohsub - 3);
  const int ohb   = ohrow_i * 128 + 16 * ((ohoct + ohrow_i) & 7) + 4 * ohwd;
  const unsigned char* myrow = &toku8[bB * TROW];       // keep-mask tokens
  const unsigned char* ohrow = &toku8[ohrow_i * TROW];  // one-hot tokens

  // one-hot for t=0
  if (ohdut) {
    int tk = ohrow[0];
    unsigned wb = ((tk == 2 * ohsub) ? 0x3F80u : 0u) |
                  ((tk == 2 * ohsub + 1) ? 0x3F800000u : 0u);
    *(unsigned*)(hb + ohb) = wb;
  }

  float c0 = 0.f, h0 = 0.f;
  unsigned mp = 0, ohp = 0;
  if (ohdut) ohp = *(const unsigned*)(ohrow);   // tokens 0..3

  for (int t = 0; t < SEQ; t += 16) {
#pragma unroll
    for (int u = 0; u < 16; ++u) {
      const int T  = t + u;
      const int PB = (u & 1) * 2048, PN = PB ^ 2048;
      __syncthreads();   // hbuf[PB] ready; LDS-only -> lgkmcnt drain

      f32x4 acc = {0.f, 0.f, 0.f, 0.f};
      if (compute) {
        bf16x8 Bf0 = *(const bf16x8*)(hb + PB + rb0);
        bf16x8 Bf1 = *(const bf16x8*)(hb + PB + rb1);
        if ((u & 3) == 0) mp = *(const unsigned*)(myrow + T);   // tokens T..T+3
        acc = __builtin_amdgcn_mfma_f32_16x16x32_bf16(Af0, Bf0, acc, 0, 0, 0);
        acc = __builtin_amdgcn_mfma_f32_16x16x32_bf16(Af1, Bf1, acc, 0, 0, 0);
      }

      // one-hot for step T+1 into hbuf[PN] (waves 13/14 only)
      if (ohdut && T + 1 < SEQ) {
        int tk = (ohp >> (8 * ((u + 1) & 3))) & 0xFF;
        unsigned wb = ((tk == 2 * ohsub) ? 0x3F80u : 0u) |
                      ((tk == 2 * ohsub + 1) ? 0x3F800000u : 0u);
        *(unsigned*)(hb + PN + ohb) = wb;
        if (((u + 1) & 3) == 3 && T + 2 < SEQ)
          ohp = *(const unsigned*)(ohrow + T + 2);   // refresh: words T+2..T+5
      }

      if (compute) {
        // fused-fraction LSTM cell: 5 exp2 + 2 rcp
        float A = __builtin_amdgcn_exp2f(acc[0]);   // i (pre-scaled -log2e)
        float B = __builtin_amdgcn_exp2f(acc[1]);   // f
        float C = __builtin_amdgcn_exp2f(acc[2]);   // g (pre-scaled -2log2e)
        float G = __builtin_amdgcn_exp2f(acc[3]);   // o
        float a1 = 1.0f + A, bb1 = 1.0f + B, c1 = 1.0f + C, g1 = 1.0f + G;
        float P   = a1 * c1;
        float t1  = __builtin_fmaf(-C, bb1, bb1);          // (1+B)(1-C)
        float num = __builtin_fmaf(c0, P, t1);             // c(1+A)(1+C)+(1+B)(1-C)
        float den = P * bb1;
        float cn  = num * __builtin_amdgcn_rcpf(den);
        cn = fminf(fmaxf(cn, -30.0f), 30.0f);              // keep H finite
        float H   = __builtin_amdgcn_exp2f(cn * -2.885390082f);
        float hd  = g1 * (1.0f + H);
        float hn  = (1.0f - H) * __builtin_amdgcn_rcpf(hd); // o*tanh(cn)
        const bool keep = (((mp >> (8 * (u & 3))) & 0xFF) != 0);
        c0 = keep ? cn : c0;
        h0 = keep ? hn : h0;
        if (hval) *(short*)(hb + PN + hwb) = f2bf(h0);
      }
    }
  }

  // ---- final h -> MLP -> sigmoid
  if (hval) hfin[bB * 52 + jhw] = h0;
  __syncthreads();
  for (int idx = tid; idx < 16 * 64; idx += 1024) {
    int b = idx >> 6, m = idx & 63;
    if (m < HID) {
      float s = b1[m];
      for (int j2 = 0; j2 < HID; ++j2) s += hfin[b * 52 + j2] * W1[m * HID + j2];
      mlp_hid[b * 52 + m] = s;
    }
  }
  __syncthreads();
  if (tid < 16) {
    float s = b2[0];
    for (int m2 = 0; m2 < HID; ++m2) s += mlp_hid[tid * 52 + m2] * W2[m2];
    out[b0 + tid] = fsigm(s);
  }
}

extern "C" void kernel_launch(void* const* d_in, const int* in_sizes, int n_in,
                              void* d_out, int out_size, void* d_ws, size_t ws_size,
                              hipStream_t stream) {
  const int*   tokens = (const int*)  d_in[0];
  const float* emb    = (const float*)d_in[1];
  const float* W_ih   = (const float*)d_in[2];
  const float* W_hh   = (const float*)d_in[3];
  const float* b_ih   = (const float*)d_in[4];
  const float* b_hh   = (const float*)d_in[5];
  const float* W1     = (const float*)d_in[6];
  const float* b1     = (const float*)d_in[7];
  const float* W2     = (const float*)d_in[8];
  const float* b2     = (const float*)d_in[9];
  float* outp  = (float*)d_out;
  short* Apack = (short*)d_ws;                 // 13312 bf16 = 26.6 KB

  hipLaunchKernelGGL(prep_kernel, dim3(52), dim3(256), 0, stream,
                     emb, W_ih, W_hh, b_ih, b_hh, Apack);
  hipLaunchKernelGGL(lstm_kernel, dim3(BATCH / 16), dim3(1024), 0, stream,
                     tokens, Apack, W1, b1, W2, b2, outp);
}